// Round 17
// baseline (263.938 us; speedup 1.0000x reference)
//
#include <hip/hip_runtime.h>
#include <math.h>

// Static problem dims
#define B_   2
#define N_   6
#define D_   60
#define FH_  28
#define FW_  60
#define C_   64
#define NX_  200
#define NY_  200
#define HW_  (FH_*FW_)       // 1680
#define NPIX_ (B_*N_*HW_)    // 20160

// ---------------------------------------------------------------------------
// Kernel 1: numpy.linalg.inv on FLOAT32 = OpenBLAS sgesv(A, I), x86-64
// (Haswell/Zen kernels, runtime-dispatched by OpenBLAS itself):
//   - sgetf2: isamax first-strict-max pivoting; reciprocal-multiply column
//     scaling (1/ajj via division, then scal-multiply); sger with FMA.
//   - sgetrs: slaswp forward on B=I; strsm L-Lower-Unit with FMA updates;
//     strsm L-Upper-NonUnit with PACKED-RECIPROCAL diagonal (copy routine
//     stores 1/diag; solve MULTIPLIES), FMA updates.
// numpy linearizes row-major -> Fortran order, so LAPACK factors A itself.
// All arithmetic strictly float32.  [R14's inverse — best cell, kept as-is]
// ---------------------------------------------------------------------------
__global__ void k_invert_ob32(const float* __restrict__ l2i, float* __restrict__ minv_out) {
#pragma clang fp contract(off)
    int m = blockIdx.x * blockDim.x + threadIdx.x;
    if (m >= B_ * N_) return;
    float a[4][4];
    for (int r = 0; r < 4; r++)
        for (int c = 0; c < 4; c++)
            a[r][c] = l2i[m * 16 + r * 4 + c];
    int ipiv[4];

    // ---- sgetf2 on A (row pivoting), reciprocal-multiply scal, FMA ger ----
    for (int j = 0; j < 4; j++) {
        int jp = j; float amax = fabsf(a[j][j]);
        for (int i = j + 1; i < 4; i++) {
            float v = fabsf(a[i][j]);
            if (v > amax) { amax = v; jp = i; }   // isamax: first strict max
        }
        ipiv[j] = jp;
        if (jp != j)
            for (int c = 0; c < 4; c++) { float t = a[j][c]; a[j][c] = a[jp][c]; a[jp][c] = t; }
        if (a[j][j] != 0.0f) {
            float rcp = 1.0f / a[j][j];           // 1/ajj via division, then multiply
            for (int i = j + 1; i < 4; i++) a[i][j] = a[i][j] * rcp;
        }
        // sger: temp = -u_jk (exact negation), FMA update
        for (int k = j + 1; k < 4; k++) {
            float temp = -a[j][k];
            if (temp != 0.0f)
                for (int i = j + 1; i < 4; i++)
                    a[i][k] = fmaf(a[i][j], temp, a[i][k]);
        }
    }

    // ---- B = I, slaswp forward ----
    float bmat[4][4];
    for (int r = 0; r < 4; r++)
        for (int c = 0; c < 4; c++) bmat[r][c] = (r == c) ? 1.0f : 0.0f;
    for (int j = 0; j < 4; j++) {
        int jp = ipiv[j];
        if (jp != j)
            for (int c = 0; c < 4; c++) { float t = bmat[j][c]; bmat[j][c] = bmat[jp][c]; bmat[jp][c] = t; }
    }

    // ---- strsm Left Lower NoTrans Unit, FMA updates ----
    for (int c = 0; c < 4; c++)
        for (int k = 0; k < 4; k++) {
            float bk = bmat[k][c];
            if (bk != 0.0f)
                for (int i = k + 1; i < 4; i++)
                    bmat[i][c] = fmaf(-bk, a[i][k], bmat[i][c]);
        }

    // ---- strsm Left Upper NoTrans NonUnit, packed-reciprocal multiply ----
    float dinv[4];
    for (int k = 0; k < 4; k++) dinv[k] = 1.0f / a[k][k];   // trsm pack: 1/diag
    for (int c = 0; c < 4; c++)
        for (int k = 3; k >= 0; k--) {
            float bk = bmat[k][c];
            if (bk != 0.0f) {
                bk = bk * dinv[k];                // MULTIPLY by reciprocal
                bmat[k][c] = bk;
                for (int i = 0; i < k; i++)
                    bmat[i][c] = fmaf(-bk, a[i][k], bmat[i][c]);
            }
        }

    for (int r = 0; r < 4; r++)
        for (int c = 0; c < 4; c++)
            minv_out[m * 16 + r * 4 + c] = bmat[r][c];
}

// ---------------------------------------------------------------------------
// Kernel 2: softmax over D per pixel. depth (BN,D,FH,FW) -> wt (NPIX, D)
// ---------------------------------------------------------------------------
__global__ void k_softmax(const float* __restrict__ depth, float* __restrict__ wt) {
    int p = blockIdx.x * blockDim.x + threadIdx.x;
    if (p >= NPIX_) return;
    int bn = p / HW_;
    int hw = p - bn * HW_;
    const float* dptr = depth + (size_t)bn * D_ * HW_ + hw;
    float v[D_];
    float mx = -1e30f;
    #pragma unroll
    for (int d = 0; d < D_; d++) { v[d] = dptr[(size_t)d * HW_]; mx = fmaxf(mx, v[d]); }
    float s = 0.f;
    #pragma unroll
    for (int d = 0; d < D_; d++) { v[d] = expf(v[d] - mx); s += v[d]; }
    float is = 1.f / s;
    float* o = wt + (size_t)p * D_;
    #pragma unroll
    for (int d = 0; d < D_; d++) o[d] = v[d] * is;
}

// ---------------------------------------------------------------------------
// Kernel 3: transpose feats (BN,C,HW) -> ft (BN,HW,C), LDS tiled 64x64.
// ---------------------------------------------------------------------------
__global__ void k_tfeat(const float* __restrict__ feats, float* __restrict__ ft) {
    __shared__ float tile[64][65];
    int bn = blockIdx.y;
    int p0 = blockIdx.x * 64;
    int tx = threadIdx.x & 63;
    int ty = threadIdx.x >> 6;  // 0..3
    const float* src = feats + (size_t)bn * C_ * HW_;
    #pragma unroll
    for (int k = 0; k < 16; k++) {
        int c = ty * 16 + k;
        int p = p0 + tx;
        if (p < HW_) tile[c][tx] = src[(size_t)c * HW_ + p];
    }
    __syncthreads();
    float* dst = ft + (size_t)bn * HW_ * C_;
    #pragma unroll
    for (int k = 0; k < 16; k++) {
        int pl = ty * 16 + k;
        int p = p0 + pl;
        if (p < HW_) dst[(size_t)p * C_ + tx] = tile[tx][pl];
    }
}

// ---------------------------------------------------------------------------
// Kernel 4: scatter. One wave per pixel. Geometry in FLOAT32 = numpy einsum
// BASELINE build (einsum_sumprod.c.src is NOT in the dispatch system):
// x86 baseline SSE3 / aarch64 NEON, count=4 == vstep -> one SIMD muladd
// block (no FMA in baseline: products are PLAIN-ROUNDED muls into zero acc),
// then npyv_sum pairwise horizontal add:  g = (t0 + t1) + (t2 + t3).
// f32 quantize with division, trunc toward zero (= astype(int32)).
// ---------------------------------------------------------------------------
__global__ void k_scatter(const float* __restrict__ frustum,
                          const float* __restrict__ minv,
                          const float* __restrict__ wt,
                          const float* __restrict__ ft,
                          const float* __restrict__ dxp,
                          const float* __restrict__ bxp,
                          float* __restrict__ acc) {
#pragma clang fp contract(off)
    int gtid = blockIdx.x * blockDim.x + threadIdx.x;
    int wid = gtid >> 6;          // pixel index
    int lane = threadIdx.x & 63;
    if (wid >= NPIX_) return;
    int bn = wid / HW_;
    int hw = wid - bn * HW_;
    int h = hw / FW_;
    int w = hw - h * FW_;
    int b = bn / N_;

    float f = ft[(size_t)wid * C_ + lane];

    int enc = -1;
    float wd = 0.f;
    if (lane < D_) {
        wd = wt[(size_t)wid * D_ + lane];
        const float* fr = frustum + ((size_t)((size_t)lane * FH_ + h) * FW_ + w) * 3;
        float u = fr[0], v = fr[1], dd = fr[2];
        float dm = fmaxf(dd, 1e-5f);
        float p0 = u * dm;
        float p1 = v * dm;
        float p2 = dd;
        const float* M = minv + (size_t)bn * 16;
        // numpy baseline einsum: rounded products, pairwise hadd (01)(23)
        float x0 = M[0] * p0, x1 = M[1] * p1, x2 = M[2] * p2, x3 = M[3] * 1.0f;
        float gx = (x0 + x1) + (x2 + x3);
        float y0 = M[4] * p0, y1 = M[5] * p1, y2 = M[6] * p2, y3 = M[7] * 1.0f;
        float gy = (y0 + y1) + (y2 + y3);
        float z0 = M[8] * p0, z1 = M[9] * p1, z2 = M[10] * p2, z3 = M[11] * 1.0f;
        float gz = (z0 + z1) + (z2 + z3);
        // lb = bx - dx/2 (f32), f32 quantize, trunc toward zero
        float lb0 = bxp[0] - dxp[0] * 0.5f;
        float lb1 = bxp[1] - dxp[1] * 0.5f;
        float lb2 = bxp[2] - dxp[2] * 0.5f;
        float qx = (gx - lb0) / dxp[0];
        float qy = (gy - lb1) / dxp[1];
        float qz = (gz - lb2) / dxp[2];
        int ix = (int)qx;
        int iy = (int)qy;
        int iz = (int)qz;
        if (ix >= 0 && ix < NX_ && iy >= 0 && iy < NY_ && iz == 0)
            enc = (((b * NX_) + ix) * NY_ + iy) * C_;
    }

    for (int j = 0; j < D_; j++) {
        int e = __shfl(enc, j, 64);
        float wj = __shfl(wd, j, 64);
        if (e >= 0) atomicAdd(&acc[(size_t)e + lane], wj * f);
    }
}

// ---------------------------------------------------------------------------
// Kernel 5: transpose acc (B, NX*NY, C) -> out (B, C, NX*NY).
// ---------------------------------------------------------------------------
__global__ void k_out(const float* __restrict__ acc, float* __restrict__ out) {
    __shared__ float tile[64][65];
    int b = blockIdx.y;
    int p0 = blockIdx.x * 64;
    int tx = threadIdx.x & 63;
    int ty = threadIdx.x >> 6;
    const float* src = acc + (size_t)b * (NX_ * NY_) * C_;
    #pragma unroll
    for (int k = 0; k < 16; k++) {
        int pl = ty * 16 + k;
        tile[pl][tx] = src[(size_t)(p0 + pl) * C_ + tx];
    }
    __syncthreads();
    float* dst = out + (size_t)b * C_ * (NX_ * NY_);
    #pragma unroll
    for (int k = 0; k < 16; k++) {
        int c = ty * 16 + k;
        dst[(size_t)c * (NX_ * NY_) + p0 + tx] = tile[tx][c];
    }
}

// ---------------------------------------------------------------------------
extern "C" void kernel_launch(void* const* d_in, const int* in_sizes, int n_in,
                              void* d_out, int out_size, void* d_ws, size_t ws_size,
                              hipStream_t stream) {
    const float* feats = (const float*)d_in[0];
    const float* depth = (const float*)d_in[1];
    const float* l2i   = (const float*)d_in[2];
    const float* frust = (const float*)d_in[3];
    const float* dx    = (const float*)d_in[4];
    const float* bx    = (const float*)d_in[5];
    float* out = (float*)d_out;

    char* ws = (char*)d_ws;
    float* minv = (float*)ws;                                     // 12*16*4 = 768 B (pad 2048)
    float* wt  = (float*)(ws + 2048);                             // 20160*60*4 = 4,838,400
    float* ft  = (float*)(ws + 2048 + 4838400);                   // 20160*64*4 = 5,160,960
    float* acc = (float*)(ws + 2048 + 4838400 + 5160960);         // 2*200*200*64*4 = 20,480,000

    hipMemsetAsync(acc, 0, (size_t)B_ * NX_ * NY_ * C_ * sizeof(float), stream);
    k_invert_ob32<<<1, 64, 0, stream>>>(l2i, minv);
    k_softmax<<<(NPIX_ + 255) / 256, 256, 0, stream>>>(depth, wt);
    k_tfeat<<<dim3((HW_ + 63) / 64, B_ * N_), 256, 0, stream>>>(feats, ft);
    k_scatter<<<(NPIX_ * 64) / 256, 256, 0, stream>>>(frust, minv, wt, ft, dx, bx, acc);
    k_out<<<dim3((NX_ * NY_) / 64, B_), 256, 0, stream>>>(acc, out);
}

// Round 18
// 89.109 us; speedup vs baseline: 2.9620x; 2.9620x over previous
//
#include <hip/hip_runtime.h>
#include <math.h>

// Static problem dims
#define B_   2
#define N_   6
#define D_   60
#define FH_  28
#define FW_  60
#define C_   64
#define NX_  200
#define NY_  200
#define HW_  (FH_*FW_)       // 1680
#define NPIX_ (B_*N_*HW_)    // 20160

// ---------------------------------------------------------------------------
// Kernel 1: numpy.linalg.inv on FLOAT32 = OpenBLAS sgesv(A, I)  [VERIFIED R17]
// ---------------------------------------------------------------------------
__global__ void k_invert_ob32(const float* __restrict__ l2i, float* __restrict__ minv_out) {
#pragma clang fp contract(off)
    int m = blockIdx.x * blockDim.x + threadIdx.x;
    if (m >= B_ * N_) return;
    float a[4][4];
    for (int r = 0; r < 4; r++)
        for (int c = 0; c < 4; c++)
            a[r][c] = l2i[m * 16 + r * 4 + c];
    int ipiv[4];

    for (int j = 0; j < 4; j++) {
        int jp = j; float amax = fabsf(a[j][j]);
        for (int i = j + 1; i < 4; i++) {
            float v = fabsf(a[i][j]);
            if (v > amax) { amax = v; jp = i; }
        }
        ipiv[j] = jp;
        if (jp != j)
            for (int c = 0; c < 4; c++) { float t = a[j][c]; a[j][c] = a[jp][c]; a[jp][c] = t; }
        if (a[j][j] != 0.0f) {
            float rcp = 1.0f / a[j][j];
            for (int i = j + 1; i < 4; i++) a[i][j] = a[i][j] * rcp;
        }
        for (int k = j + 1; k < 4; k++) {
            float temp = -a[j][k];
            if (temp != 0.0f)
                for (int i = j + 1; i < 4; i++)
                    a[i][k] = fmaf(a[i][j], temp, a[i][k]);
        }
    }

    float bmat[4][4];
    for (int r = 0; r < 4; r++)
        for (int c = 0; c < 4; c++) bmat[r][c] = (r == c) ? 1.0f : 0.0f;
    for (int j = 0; j < 4; j++) {
        int jp = ipiv[j];
        if (jp != j)
            for (int c = 0; c < 4; c++) { float t = bmat[j][c]; bmat[j][c] = bmat[jp][c]; bmat[jp][c] = t; }
    }

    for (int c = 0; c < 4; c++)
        for (int k = 0; k < 4; k++) {
            float bk = bmat[k][c];
            if (bk != 0.0f)
                for (int i = k + 1; i < 4; i++)
                    bmat[i][c] = fmaf(-bk, a[i][k], bmat[i][c]);
        }

    float dinv[4];
    for (int k = 0; k < 4; k++) dinv[k] = 1.0f / a[k][k];
    for (int c = 0; c < 4; c++)
        for (int k = 3; k >= 0; k--) {
            float bk = bmat[k][c];
            if (bk != 0.0f) {
                bk = bk * dinv[k];
                bmat[k][c] = bk;
                for (int i = 0; i < k; i++)
                    bmat[i][c] = fmaf(-bk, a[i][k], bmat[i][c]);
            }
        }

    for (int r = 0; r < 4; r++)
        for (int c = 0; c < 4; c++)
            minv_out[m * 16 + r * 4 + c] = bmat[r][c];
}

// ---------------------------------------------------------------------------
// Kernel 2: softmax over D per pixel. depth (BN,D,FH,FW) -> wt (NPIX, D)
// ---------------------------------------------------------------------------
__global__ void k_softmax(const float* __restrict__ depth, float* __restrict__ wt) {
    int p = blockIdx.x * blockDim.x + threadIdx.x;
    if (p >= NPIX_) return;
    int bn = p / HW_;
    int hw = p - bn * HW_;
    const float* dptr = depth + (size_t)bn * D_ * HW_ + hw;
    float v[D_];
    float mx = -1e30f;
    #pragma unroll
    for (int d = 0; d < D_; d++) { v[d] = dptr[(size_t)d * HW_]; mx = fmaxf(mx, v[d]); }
    float s = 0.f;
    #pragma unroll
    for (int d = 0; d < D_; d++) { v[d] = expf(v[d] - mx); s += v[d]; }
    float is = 1.f / s;
    float* o = wt + (size_t)p * D_;
    #pragma unroll
    for (int d = 0; d < D_; d++) o[d] = v[d] * is;
}

// ---------------------------------------------------------------------------
// Kernel 3: transpose feats (BN,C,HW) -> ft (BN,HW,C), LDS tiled 64x64.
// ---------------------------------------------------------------------------
__global__ void k_tfeat(const float* __restrict__ feats, float* __restrict__ ft) {
    __shared__ float tile[64][65];
    int bn = blockIdx.y;
    int p0 = blockIdx.x * 64;
    int tx = threadIdx.x & 63;
    int ty = threadIdx.x >> 6;  // 0..3
    const float* src = feats + (size_t)bn * C_ * HW_;
    #pragma unroll
    for (int k = 0; k < 16; k++) {
        int c = ty * 16 + k;
        int p = p0 + tx;
        if (p < HW_) tile[c][tx] = src[(size_t)c * HW_ + p];
    }
    __syncthreads();
    float* dst = ft + (size_t)bn * HW_ * C_;
    #pragma unroll
    for (int k = 0; k < 16; k++) {
        int pl = ty * 16 + k;
        int p = p0 + pl;
        if (p < HW_) dst[(size_t)p * C_ + tx] = tile[tx][pl];
    }
}

// ---------------------------------------------------------------------------
// Kernel 4: scatter2 — one wave per (bn, w, d) column. Lanes 0..27 compute
// the 28 per-h voxel encs BIT-IDENTICALLY to the verified R17 path; then a
// ballot-grouping loop does one register-accumulated sum + ONE atomicAdd per
// DISTINCT enc (usually 1: (gx,gy) are v-independent for z-axis extrinsics).
// Cuts atomic payload ~10-25x; reads ft via coalesced 256B L2 loads.
// ---------------------------------------------------------------------------
__global__ void k_scatter2(const float* __restrict__ frustum,
                           const float* __restrict__ minv,
                           const float* __restrict__ wt,
                           const float* __restrict__ ft,
                           const float* __restrict__ dxp,
                           const float* __restrict__ bxp,
                           float* __restrict__ acc) {
#pragma clang fp contract(off)
    int gtid = blockIdx.x * blockDim.x + threadIdx.x;
    int wvid = gtid >> 6;                 // (bn, w, d) column index
    int lane = threadIdx.x & 63;
    if (wvid >= B_ * N_ * FW_ * D_) return;
    int d  = wvid % D_;
    int w  = (wvid / D_) % FW_;
    int bn = wvid / (D_ * FW_);
    int b  = bn / N_;
    int bnbase = bn * HW_;                // pixel base for this camera

    int myenc = -1;
    float mywt = 0.f;
    if (lane < FH_) {
        int h = lane;
        int pix = bnbase + h * FW_ + w;
        mywt = wt[(size_t)pix * D_ + d];
        const float* fr = frustum + ((size_t)((size_t)d * FH_ + h) * FW_ + w) * 3;
        float u = fr[0], v = fr[1], dd = fr[2];
        float dm = fmaxf(dd, 1e-5f);
        float p0 = u * dm;
        float p1 = v * dm;
        float p2 = dd;
        const float* M = minv + (size_t)bn * 16;
        // numpy baseline einsum: rounded products, pairwise hadd (01)(23)
        float x0 = M[0] * p0, x1 = M[1] * p1, x2 = M[2] * p2, x3 = M[3] * 1.0f;
        float gx = (x0 + x1) + (x2 + x3);
        float y0 = M[4] * p0, y1 = M[5] * p1, y2 = M[6] * p2, y3 = M[7] * 1.0f;
        float gy = (y0 + y1) + (y2 + y3);
        float z0 = M[8] * p0, z1 = M[9] * p1, z2 = M[10] * p2, z3 = M[11] * 1.0f;
        float gz = (z0 + z1) + (z2 + z3);
        float lb0 = bxp[0] - dxp[0] * 0.5f;
        float lb1 = bxp[1] - dxp[1] * 0.5f;
        float lb2 = bxp[2] - dxp[2] * 0.5f;
        float qx = (gx - lb0) / dxp[0];
        float qy = (gy - lb1) / dxp[1];
        float qz = (gz - lb2) / dxp[2];
        int ix = (int)qx;
        int iy = (int)qy;
        int iz = (int)qz;
        if (ix >= 0 && ix < NX_ && iy >= 0 && iy < NY_ && iz == 0)
            myenc = (((b * NX_) + ix) * NY_ + iy) * C_;
    }

    // group by distinct enc; one register-sum + one atomic per group
    unsigned long long processed = 0;
    for (int j = 0; j < FH_; ++j) {
        if (processed & (1ull << j)) continue;
        int e = __shfl(myenc, j, 64);
        unsigned long long mm = __ballot(lane < FH_ && myenc == e);
        processed |= mm;
        if (e < 0) continue;
        float s = 0.f;
        unsigned long long t = mm;
        while (t) {
            int k = __builtin_ctzll(t);
            t &= t - 1;
            float wk = __shfl(mywt, k, 64);
            int pk = bnbase + k * FW_ + w;
            s = fmaf(wk, ft[(size_t)pk * C_ + lane], s);
        }
        atomicAdd(&acc[(size_t)e + lane], s);
    }
}

// ---------------------------------------------------------------------------
// Kernel 5: transpose acc (B, NX*NY, C) -> out (B, C, NX*NY).
// ---------------------------------------------------------------------------
__global__ void k_out(const float* __restrict__ acc, float* __restrict__ out) {
    __shared__ float tile[64][65];
    int b = blockIdx.y;
    int p0 = blockIdx.x * 64;
    int tx = threadIdx.x & 63;
    int ty = threadIdx.x >> 6;
    const float* src = acc + (size_t)b * (NX_ * NY_) * C_;
    #pragma unroll
    for (int k = 0; k < 16; k++) {
        int pl = ty * 16 + k;
        tile[pl][tx] = src[(size_t)(p0 + pl) * C_ + tx];
    }
    __syncthreads();
    float* dst = out + (size_t)b * C_ * (NX_ * NY_);
    #pragma unroll
    for (int k = 0; k < 16; k++) {
        int c = ty * 16 + k;
        dst[(size_t)c * (NX_ * NY_) + p0 + tx] = tile[tx][c];
    }
}

// ---------------------------------------------------------------------------
extern "C" void kernel_launch(void* const* d_in, const int* in_sizes, int n_in,
                              void* d_out, int out_size, void* d_ws, size_t ws_size,
                              hipStream_t stream) {
    const float* feats = (const float*)d_in[0];
    const float* depth = (const float*)d_in[1];
    const float* l2i   = (const float*)d_in[2];
    const float* frust = (const float*)d_in[3];
    const float* dx    = (const float*)d_in[4];
    const float* bx    = (const float*)d_in[5];
    float* out = (float*)d_out;

    char* ws = (char*)d_ws;
    float* minv = (float*)ws;                                     // 12*16*4 = 768 B (pad 2048)
    float* wt  = (float*)(ws + 2048);                             // 20160*60*4 = 4,838,400
    float* ft  = (float*)(ws + 2048 + 4838400);                   // 20160*64*4 = 5,160,960
    float* acc = (float*)(ws + 2048 + 4838400 + 5160960);         // 2*200*200*64*4 = 20,480,000

    hipMemsetAsync(acc, 0, (size_t)B_ * NX_ * NY_ * C_ * sizeof(float), stream);
    k_invert_ob32<<<1, 64, 0, stream>>>(l2i, minv);
    k_softmax<<<(NPIX_ + 255) / 256, 256, 0, stream>>>(depth, wt);
    k_tfeat<<<dim3((HW_ + 63) / 64, B_ * N_), 256, 0, stream>>>(feats, ft);
    int nwaves = B_ * N_ * FW_ * D_;                              // 43200
    k_scatter2<<<(nwaves * 64 + 255) / 256, 256, 0, stream>>>(frust, minv, wt, ft, dx, bx, acc);
    k_out<<<dim3((NX_ * NY_) / 64, B_), 256, 0, stream>>>(acc, out);
}

// Round 19
// 84.041 us; speedup vs baseline: 3.1406x; 1.0603x over previous
//
#include <hip/hip_runtime.h>
#include <math.h>

// Static problem dims
#define B_   2
#define N_   6
#define D_   60
#define FH_  28
#define FW_  60
#define C_   64
#define NX_  200
#define NY_  200
#define HW_  (FH_*FW_)       // 1680
#define NPIX_ (B_*N_*HW_)    // 20160
#define DSPLIT 4
#define DCHUNK (D_/DSPLIT)   // 15

// ---------------------------------------------------------------------------
// Kernel 1: numpy.linalg.inv on FLOAT32 = OpenBLAS sgesv(A, I)  [VERIFIED R17]
// ---------------------------------------------------------------------------
__global__ void k_invert_ob32(const float* __restrict__ l2i, float* __restrict__ minv_out) {
#pragma clang fp contract(off)
    int m = blockIdx.x * blockDim.x + threadIdx.x;
    if (m >= B_ * N_) return;
    float a[4][4];
    for (int r = 0; r < 4; r++)
        for (int c = 0; c < 4; c++)
            a[r][c] = l2i[m * 16 + r * 4 + c];
    int ipiv[4];

    for (int j = 0; j < 4; j++) {
        int jp = j; float amax = fabsf(a[j][j]);
        for (int i = j + 1; i < 4; i++) {
            float v = fabsf(a[i][j]);
            if (v > amax) { amax = v; jp = i; }
        }
        ipiv[j] = jp;
        if (jp != j)
            for (int c = 0; c < 4; c++) { float t = a[j][c]; a[j][c] = a[jp][c]; a[jp][c] = t; }
        if (a[j][j] != 0.0f) {
            float rcp = 1.0f / a[j][j];
            for (int i = j + 1; i < 4; i++) a[i][j] = a[i][j] * rcp;
        }
        for (int k = j + 1; k < 4; k++) {
            float temp = -a[j][k];
            if (temp != 0.0f)
                for (int i = j + 1; i < 4; i++)
                    a[i][k] = fmaf(a[i][j], temp, a[i][k]);
        }
    }

    float bmat[4][4];
    for (int r = 0; r < 4; r++)
        for (int c = 0; c < 4; c++) bmat[r][c] = (r == c) ? 1.0f : 0.0f;
    for (int j = 0; j < 4; j++) {
        int jp = ipiv[j];
        if (jp != j)
            for (int c = 0; c < 4; c++) { float t = bmat[j][c]; bmat[j][c] = bmat[jp][c]; bmat[jp][c] = t; }
    }

    for (int c = 0; c < 4; c++)
        for (int k = 0; k < 4; k++) {
            float bk = bmat[k][c];
            if (bk != 0.0f)
                for (int i = k + 1; i < 4; i++)
                    bmat[i][c] = fmaf(-bk, a[i][k], bmat[i][c]);
        }

    float dinv[4];
    for (int k = 0; k < 4; k++) dinv[k] = 1.0f / a[k][k];
    for (int c = 0; c < 4; c++)
        for (int k = 3; k >= 0; k--) {
            float bk = bmat[k][c];
            if (bk != 0.0f) {
                bk = bk * dinv[k];
                bmat[k][c] = bk;
                for (int i = 0; i < k; i++)
                    bmat[i][c] = fmaf(-bk, a[i][k], bmat[i][c]);
            }
        }

    for (int r = 0; r < 4; r++)
        for (int c = 0; c < 4; c++)
            minv_out[m * 16 + r * 4 + c] = bmat[r][c];
}

// ---------------------------------------------------------------------------
// Kernel 2: softmax over D per pixel. depth (BN,D,FH,FW) -> wt (NPIX, D)
// ---------------------------------------------------------------------------
__global__ void k_softmax(const float* __restrict__ depth, float* __restrict__ wt) {
    int p = blockIdx.x * blockDim.x + threadIdx.x;
    if (p >= NPIX_) return;
    int bn = p / HW_;
    int hw = p - bn * HW_;
    const float* dptr = depth + (size_t)bn * D_ * HW_ + hw;
    float v[D_];
    float mx = -1e30f;
    #pragma unroll
    for (int d = 0; d < D_; d++) { v[d] = dptr[(size_t)d * HW_]; mx = fmaxf(mx, v[d]); }
    float s = 0.f;
    #pragma unroll
    for (int d = 0; d < D_; d++) { v[d] = expf(v[d] - mx); s += v[d]; }
    float is = 1.f / s;
    float* o = wt + (size_t)p * D_;
    #pragma unroll
    for (int d = 0; d < D_; d++) o[d] = v[d] * is;
}

// ---------------------------------------------------------------------------
// Kernel 3: transpose feats (BN,C,HW) -> ft (BN,HW,C), LDS tiled 64x64.
// ---------------------------------------------------------------------------
__global__ void k_tfeat(const float* __restrict__ feats, float* __restrict__ ft) {
    __shared__ float tile[64][65];
    int bn = blockIdx.y;
    int p0 = blockIdx.x * 64;
    int tx = threadIdx.x & 63;
    int ty = threadIdx.x >> 6;  // 0..3
    const float* src = feats + (size_t)bn * C_ * HW_;
    #pragma unroll
    for (int k = 0; k < 16; k++) {
        int c = ty * 16 + k;
        int p = p0 + tx;
        if (p < HW_) tile[c][tx] = src[(size_t)c * HW_ + p];
    }
    __syncthreads();
    float* dst = ft + (size_t)bn * HW_ * C_;
    #pragma unroll
    for (int k = 0; k < 16; k++) {
        int pl = ty * 16 + k;
        int p = p0 + pl;
        if (p < HW_) dst[(size_t)p * C_ + tx] = tile[tx][pl];
    }
}

// ---------------------------------------------------------------------------
// Kernel 4: scatter3 — one wave per (bn, w, d-chunk of 15). The 28 ft rows
// of the (bn,w) column are d-invariant: loaded ONCE into registers (28
// coalesced 256B loads). Per d: bit-identical geometry (u,v hoisted from
// frustum, dd=(float)(d+1) exact), ballot-grouping, then per distinct enc a
// fully-unrolled predicated 28-FMA register reduction + ONE atomicAdd.
// Removes the serial 28-deep L2-load chain of R18.
// ---------------------------------------------------------------------------
__global__ void k_scatter3(const float* __restrict__ frustum,
                           const float* __restrict__ minv,
                           const float* __restrict__ wt,
                           const float* __restrict__ ft,
                           const float* __restrict__ dxp,
                           const float* __restrict__ bxp,
                           float* __restrict__ acc) {
#pragma clang fp contract(off)
    int gtid = blockIdx.x * blockDim.x + threadIdx.x;
    int wvid = gtid >> 6;
    int lane = threadIdx.x & 63;
    if (wvid >= B_ * N_ * FW_ * DSPLIT) return;
    int dq = wvid % DSPLIT;
    int w  = (wvid / DSPLIT) % FW_;
    int bn = wvid / (DSPLIT * FW_);
    int b  = bn / N_;
    int bnbase = bn * HW_;

    // d-invariant ft rows -> registers (lane = channel c)
    float ftreg[FH_];
    #pragma unroll
    for (int h = 0; h < FH_; h++)
        ftreg[h] = ft[(size_t)(bnbase + h * FW_ + w) * C_ + lane];

    // d-invariant geometry constants
    float u = frustum[w * 3 + 0];              // xs: depends on w only
    float v = 0.f;
    int pix = 0;
    if (lane < FH_) {
        v = frustum[((size_t)lane * FW_ + w) * 3 + 1];   // ys: h only
        pix = bnbase + lane * FW_ + w;
    }
    const float* M = minv + (size_t)bn * 16;
    float M0 = M[0], M1 = M[1], M2 = M[2],  M3 = M[3];
    float M4 = M[4], M5 = M[5], M6 = M[6],  M7 = M[7];
    float M8 = M[8], M9 = M[9], M10 = M[10], M11 = M[11];
    float dx0 = dxp[0], dx1 = dxp[1], dx2 = dxp[2];
    float lb0 = bxp[0] - dx0 * 0.5f;
    float lb1 = bxp[1] - dx1 * 0.5f;
    float lb2 = bxp[2] - dx2 * 0.5f;

    int d0 = dq * DCHUNK;
    for (int d = d0; d < d0 + DCHUNK; d++) {
        float mywt = 0.f;
        int myenc = -1;
        if (lane < FH_) {
            mywt = wt[(size_t)pix * D_ + d];
            float dd = (float)(d + 1);         // frustum ds = arange(1,61): exact
            float dm = fmaxf(dd, 1e-5f);
            float p0 = u * dm;
            float p1 = v * dm;
            float p2 = dd;
            // numpy baseline einsum: rounded products, pairwise hadd (01)(23)
            float x0 = M0 * p0, x1 = M1 * p1, x2 = M2 * p2, x3 = M3 * 1.0f;
            float gx = (x0 + x1) + (x2 + x3);
            float y0 = M4 * p0, y1 = M5 * p1, y2 = M6 * p2, y3 = M7 * 1.0f;
            float gy = (y0 + y1) + (y2 + y3);
            float z0 = M8 * p0, z1 = M9 * p1, z2 = M10 * p2, z3 = M11 * 1.0f;
            float gz = (z0 + z1) + (z2 + z3);
            float qx = (gx - lb0) / dx0;
            float qy = (gy - lb1) / dx1;
            float qz = (gz - lb2) / dx2;
            int ix = (int)qx;
            int iy = (int)qy;
            int iz = (int)qz;
            if (ix >= 0 && ix < NX_ && iy >= 0 && iy < NY_ && iz == 0)
                myenc = (((b * NX_) + ix) * NY_ + iy) * C_;
        }

        unsigned long long processed = 0;
        for (int j = 0; j < FH_; ++j) {
            if (processed & (1ull << j)) continue;
            int e = __shfl(myenc, j, 64);
            unsigned long long mm = __ballot(lane < FH_ && myenc == e);
            processed |= mm;
            if (e < 0) continue;
            float s = 0.f;
            #pragma unroll
            for (int h = 0; h < FH_; h++) {
                float wh = __shfl(mywt, h, 64);
                s = fmaf(((mm >> h) & 1ull) ? wh : 0.0f, ftreg[h], s);
            }
            atomicAdd(&acc[(size_t)e + lane], s);
        }
    }
}

// ---------------------------------------------------------------------------
// Kernel 5: transpose acc (B, NX*NY, C) -> out (B, C, NX*NY).
// ---------------------------------------------------------------------------
__global__ void k_out(const float* __restrict__ acc, float* __restrict__ out) {
    __shared__ float tile[64][65];
    int b = blockIdx.y;
    int p0 = blockIdx.x * 64;
    int tx = threadIdx.x & 63;
    int ty = threadIdx.x >> 6;
    const float* src = acc + (size_t)b * (NX_ * NY_) * C_;
    #pragma unroll
    for (int k = 0; k < 16; k++) {
        int pl = ty * 16 + k;
        tile[pl][tx] = src[(size_t)(p0 + pl) * C_ + tx];
    }
    __syncthreads();
    float* dst = out + (size_t)b * C_ * (NX_ * NY_);
    #pragma unroll
    for (int k = 0; k < 16; k++) {
        int c = ty * 16 + k;
        dst[(size_t)c * (NX_ * NY_) + p0 + tx] = tile[tx][c];
    }
}

// ---------------------------------------------------------------------------
extern "C" void kernel_launch(void* const* d_in, const int* in_sizes, int n_in,
                              void* d_out, int out_size, void* d_ws, size_t ws_size,
                              hipStream_t stream) {
    const float* feats = (const float*)d_in[0];
    const float* depth = (const float*)d_in[1];
    const float* l2i   = (const float*)d_in[2];
    const float* frust = (const float*)d_in[3];
    const float* dx    = (const float*)d_in[4];
    const float* bx    = (const float*)d_in[5];
    float* out = (float*)d_out;

    char* ws = (char*)d_ws;
    float* minv = (float*)ws;                                     // 12*16*4 = 768 B (pad 2048)
    float* wt  = (float*)(ws + 2048);                             // 20160*60*4 = 4,838,400
    float* ft  = (float*)(ws + 2048 + 4838400);                   // 20160*64*4 = 5,160,960
    float* acc = (float*)(ws + 2048 + 4838400 + 5160960);         // 2*200*200*64*4 = 20,480,000

    hipMemsetAsync(acc, 0, (size_t)B_ * NX_ * NY_ * C_ * sizeof(float), stream);
    k_invert_ob32<<<1, 64, 0, stream>>>(l2i, minv);
    k_softmax<<<(NPIX_ + 255) / 256, 256, 0, stream>>>(depth, wt);
    k_tfeat<<<dim3((HW_ + 63) / 64, B_ * N_), 256, 0, stream>>>(feats, ft);
    int nwaves = B_ * N_ * FW_ * DSPLIT;                          // 2880
    k_scatter3<<<(nwaves * 64 + 255) / 256, 256, 0, stream>>>(frust, minv, wt, ft, dx, bx, acc);
    k_out<<<dim3((NX_ * NY_) / 64, B_), 256, 0, stream>>>(acc, out);
}

// Round 20
// 68.983 us; speedup vs baseline: 3.8261x; 1.2183x over previous
//
#include <hip/hip_runtime.h>
#include <math.h>

// Static problem dims
#define B_   2
#define N_   6
#define D_   60
#define FH_  28
#define FW_  60
#define C_   64
#define NX_  200
#define NY_  200
#define HW_  (FH_*FW_)       // 1680
#define NPIX_ (B_*N_*HW_)    // 20160
#define DSPLIT 15
#define DCHUNK (D_/DSPLIT)   // 4

// ---------------------------------------------------------------------------
// Kernel 1: numpy.linalg.inv on FLOAT32 = OpenBLAS sgesv(A, I)  [VERIFIED R17]
// ---------------------------------------------------------------------------
__global__ void k_invert_ob32(const float* __restrict__ l2i, float* __restrict__ minv_out) {
#pragma clang fp contract(off)
    int m = blockIdx.x * blockDim.x + threadIdx.x;
    if (m >= B_ * N_) return;
    float a[4][4];
    for (int r = 0; r < 4; r++)
        for (int c = 0; c < 4; c++)
            a[r][c] = l2i[m * 16 + r * 4 + c];
    int ipiv[4];

    for (int j = 0; j < 4; j++) {
        int jp = j; float amax = fabsf(a[j][j]);
        for (int i = j + 1; i < 4; i++) {
            float v = fabsf(a[i][j]);
            if (v > amax) { amax = v; jp = i; }
        }
        ipiv[j] = jp;
        if (jp != j)
            for (int c = 0; c < 4; c++) { float t = a[j][c]; a[j][c] = a[jp][c]; a[jp][c] = t; }
        if (a[j][j] != 0.0f) {
            float rcp = 1.0f / a[j][j];
            for (int i = j + 1; i < 4; i++) a[i][j] = a[i][j] * rcp;
        }
        for (int k = j + 1; k < 4; k++) {
            float temp = -a[j][k];
            if (temp != 0.0f)
                for (int i = j + 1; i < 4; i++)
                    a[i][k] = fmaf(a[i][j], temp, a[i][k]);
        }
    }

    float bmat[4][4];
    for (int r = 0; r < 4; r++)
        for (int c = 0; c < 4; c++) bmat[r][c] = (r == c) ? 1.0f : 0.0f;
    for (int j = 0; j < 4; j++) {
        int jp = ipiv[j];
        if (jp != j)
            for (int c = 0; c < 4; c++) { float t = bmat[j][c]; bmat[j][c] = bmat[jp][c]; bmat[jp][c] = t; }
    }

    for (int c = 0; c < 4; c++)
        for (int k = 0; k < 4; k++) {
            float bk = bmat[k][c];
            if (bk != 0.0f)
                for (int i = k + 1; i < 4; i++)
                    bmat[i][c] = fmaf(-bk, a[i][k], bmat[i][c]);
        }

    float dinv[4];
    for (int k = 0; k < 4; k++) dinv[k] = 1.0f / a[k][k];
    for (int c = 0; c < 4; c++)
        for (int k = 3; k >= 0; k--) {
            float bk = bmat[k][c];
            if (bk != 0.0f) {
                bk = bk * dinv[k];
                bmat[k][c] = bk;
                for (int i = 0; i < k; i++)
                    bmat[i][c] = fmaf(-bk, a[i][k], bmat[i][c]);
            }
        }

    for (int r = 0; r < 4; r++)
        for (int c = 0; c < 4; c++)
            minv_out[m * 16 + r * 4 + c] = bmat[r][c];
}

// ---------------------------------------------------------------------------
// Kernel 2: softmax over D per pixel. depth (BN,D,FH,FW) -> wt (NPIX, D)
// ---------------------------------------------------------------------------
__global__ void k_softmax(const float* __restrict__ depth, float* __restrict__ wt) {
    int p = blockIdx.x * blockDim.x + threadIdx.x;
    if (p >= NPIX_) return;
    int bn = p / HW_;
    int hw = p - bn * HW_;
    const float* dptr = depth + (size_t)bn * D_ * HW_ + hw;
    float v[D_];
    float mx = -1e30f;
    #pragma unroll
    for (int d = 0; d < D_; d++) { v[d] = dptr[(size_t)d * HW_]; mx = fmaxf(mx, v[d]); }
    float s = 0.f;
    #pragma unroll
    for (int d = 0; d < D_; d++) { v[d] = expf(v[d] - mx); s += v[d]; }
    float is = 1.f / s;
    float* o = wt + (size_t)p * D_;
    #pragma unroll
    for (int d = 0; d < D_; d++) o[d] = v[d] * is;
}

// ---------------------------------------------------------------------------
// Kernel 3: transpose feats (BN,C,HW) -> ft (BN,HW,C), LDS tiled 64x64.
// ---------------------------------------------------------------------------
__global__ void k_tfeat(const float* __restrict__ feats, float* __restrict__ ft) {
    __shared__ float tile[64][65];
    int bn = blockIdx.y;
    int p0 = blockIdx.x * 64;
    int tx = threadIdx.x & 63;
    int ty = threadIdx.x >> 6;  // 0..3
    const float* src = feats + (size_t)bn * C_ * HW_;
    #pragma unroll
    for (int k = 0; k < 16; k++) {
        int c = ty * 16 + k;
        int p = p0 + tx;
        if (p < HW_) tile[c][tx] = src[(size_t)c * HW_ + p];
    }
    __syncthreads();
    float* dst = ft + (size_t)bn * HW_ * C_;
    #pragma unroll
    for (int k = 0; k < 16; k++) {
        int pl = ty * 16 + k;
        int p = p0 + pl;
        if (p < HW_) dst[(size_t)p * C_ + tx] = tile[tx][pl];
    }
}

// ---------------------------------------------------------------------------
// Kernel 4: scatter4 — one wave per (bn, w, d-chunk of 4). 28 d-invariant
// ft rows in registers; the 4 wt weights per lane arrive in ONE float4
// gather (single issued instruction). Per d: bit-identical geometry,
// ballot-grouping, predicated 28-FMA register reduction, one atomicAdd per
// distinct voxel. DSPLIT=15 gives 10800 waves (~42/CU) for latency hiding.
// ---------------------------------------------------------------------------
__global__ void k_scatter4(const float* __restrict__ frustum,
                           const float* __restrict__ minv,
                           const float* __restrict__ wt,
                           const float* __restrict__ ft,
                           const float* __restrict__ dxp,
                           const float* __restrict__ bxp,
                           float* __restrict__ acc) {
#pragma clang fp contract(off)
    int gtid = blockIdx.x * blockDim.x + threadIdx.x;
    int wvid = gtid >> 6;
    int lane = threadIdx.x & 63;
    if (wvid >= B_ * N_ * FW_ * DSPLIT) return;
    int dq = wvid % DSPLIT;
    int w  = (wvid / DSPLIT) % FW_;
    int bn = wvid / (DSPLIT * FW_);
    int b  = bn / N_;
    int bnbase = bn * HW_;
    int d0 = dq * DCHUNK;

    // d-invariant ft rows -> registers (lane = channel c)
    float ftreg[FH_];
    #pragma unroll
    for (int h = 0; h < FH_; h++)
        ftreg[h] = ft[(size_t)(bnbase + h * FW_ + w) * C_ + lane];

    // d-invariant geometry constants
    float u = frustum[w * 3 + 0];              // xs: depends on w only
    float v = 0.f;
    float4 w4 = make_float4(0.f, 0.f, 0.f, 0.f);
    if (lane < FH_) {
        v = frustum[((size_t)lane * FW_ + w) * 3 + 1];   // ys: h only
        int pix = bnbase + lane * FW_ + w;
        w4 = *reinterpret_cast<const float4*>(&wt[(size_t)pix * D_ + d0]);
    }
    const float* M = minv + (size_t)bn * 16;
    float M0 = M[0], M1 = M[1], M2 = M[2],  M3 = M[3];
    float M4 = M[4], M5 = M[5], M6 = M[6],  M7 = M[7];
    float M8 = M[8], M9 = M[9], M10 = M[10], M11 = M[11];
    float dx0 = dxp[0], dx1 = dxp[1], dx2 = dxp[2];
    float lb0 = bxp[0] - dx0 * 0.5f;
    float lb1 = bxp[1] - dx1 * 0.5f;
    float lb2 = bxp[2] - dx2 * 0.5f;

    #pragma unroll
    for (int k = 0; k < DCHUNK; k++) {
        int d = d0 + k;
        float mywt = (k == 0) ? w4.x : (k == 1) ? w4.y : (k == 2) ? w4.z : w4.w;
        int myenc = -1;
        if (lane < FH_) {
            float dd = (float)(d + 1);         // frustum ds = arange(1,61): exact
            float dm = fmaxf(dd, 1e-5f);
            float p0 = u * dm;
            float p1 = v * dm;
            float p2 = dd;
            // numpy baseline einsum: rounded products, pairwise hadd (01)(23)
            float x0 = M0 * p0, x1 = M1 * p1, x2 = M2 * p2, x3 = M3 * 1.0f;
            float gx = (x0 + x1) + (x2 + x3);
            float y0 = M4 * p0, y1 = M5 * p1, y2 = M6 * p2, y3 = M7 * 1.0f;
            float gy = (y0 + y1) + (y2 + y3);
            float z0 = M8 * p0, z1 = M9 * p1, z2 = M10 * p2, z3 = M11 * 1.0f;
            float gz = (z0 + z1) + (z2 + z3);
            float qx = (gx - lb0) / dx0;
            float qy = (gy - lb1) / dx1;
            float qz = (gz - lb2) / dx2;
            int ix = (int)qx;
            int iy = (int)qy;
            int iz = (int)qz;
            if (ix >= 0 && ix < NX_ && iy >= 0 && iy < NY_ && iz == 0)
                myenc = (((b * NX_) + ix) * NY_ + iy) * C_;
        }

        unsigned long long processed = 0;
        for (int j = 0; j < FH_; ++j) {
            if (processed & (1ull << j)) continue;
            int e = __shfl(myenc, j, 64);
            unsigned long long mm = __ballot(lane < FH_ && myenc == e);
            processed |= mm;
            if (e < 0) continue;
            float s = 0.f;
            #pragma unroll
            for (int h = 0; h < FH_; h++) {
                float wh = __shfl(mywt, h, 64);
                s = fmaf(((mm >> h) & 1ull) ? wh : 0.0f, ftreg[h], s);
            }
            atomicAdd(&acc[(size_t)e + lane], s);
        }
    }
}

// ---------------------------------------------------------------------------
// Kernel 5: transpose acc (B, NX*NY, C) -> out (B, C, NX*NY).
// ---------------------------------------------------------------------------
__global__ void k_out(const float* __restrict__ acc, float* __restrict__ out) {
    __shared__ float tile[64][65];
    int b = blockIdx.y;
    int p0 = blockIdx.x * 64;
    int tx = threadIdx.x & 63;
    int ty = threadIdx.x >> 6;
    const float* src = acc + (size_t)b * (NX_ * NY_) * C_;
    #pragma unroll
    for (int k = 0; k < 16; k++) {
        int pl = ty * 16 + k;
        tile[pl][tx] = src[(size_t)(p0 + pl) * C_ + tx];
    }
    __syncthreads();
    float* dst = out + (size_t)b * C_ * (NX_ * NY_);
    #pragma unroll
    for (int k = 0; k < 16; k++) {
        int c = ty * 16 + k;
        dst[(size_t)c * (NX_ * NY_) + p0 + tx] = tile[tx][c];
    }
}

// ---------------------------------------------------------------------------
extern "C" void kernel_launch(void* const* d_in, const int* in_sizes, int n_in,
                              void* d_out, int out_size, void* d_ws, size_t ws_size,
                              hipStream_t stream) {
    const float* feats = (const float*)d_in[0];
    const float* depth = (const float*)d_in[1];
    const float* l2i   = (const float*)d_in[2];
    const float* frust = (const float*)d_in[3];
    const float* dx    = (const float*)d_in[4];
    const float* bx    = (const float*)d_in[5];
    float* out = (float*)d_out;

    char* ws = (char*)d_ws;
    float* minv = (float*)ws;                                     // 12*16*4 = 768 B (pad 2048)
    float* wt  = (float*)(ws + 2048);                             // 20160*60*4 = 4,838,400
    float* ft  = (float*)(ws + 2048 + 4838400);                   // 20160*64*4 = 5,160,960
    float* acc = (float*)(ws + 2048 + 4838400 + 5160960);         // 2*200*200*64*4 = 20,480,000

    hipMemsetAsync(acc, 0, (size_t)B_ * NX_ * NY_ * C_ * sizeof(float), stream);
    k_invert_ob32<<<1, 64, 0, stream>>>(l2i, minv);
    k_softmax<<<(NPIX_ + 255) / 256, 256, 0, stream>>>(depth, wt);
    k_tfeat<<<dim3((HW_ + 63) / 64, B_ * N_), 256, 0, stream>>>(feats, ft);
    int nwaves = B_ * N_ * FW_ * DSPLIT;                          // 10800
    k_scatter4<<<(nwaves * 64 + 255) / 256, 256, 0, stream>>>(frust, minv, wt, ft, dx, bx, acc);
    k_out<<<dim3((NX_ * NY_) / 64, B_), 256, 0, stream>>>(acc, out);
}

// Round 21
// 61.961 us; speedup vs baseline: 4.2598x; 1.1133x over previous
//
#include <hip/hip_runtime.h>
#include <math.h>

// Static problem dims
#define B_   2
#define N_   6
#define D_   60
#define FH_  28
#define FW_  60
#define C_   64
#define NX_  200
#define NY_  200
#define HW_  (FH_*FW_)       // 1680
#define NPIX_ (B_*N_*HW_)    // 20160
#define DSPLIT 15
#define DCHUNK (D_/DSPLIT)   // 4
#define ACC_N4 ((B_*NX_*NY_*C_)/4)   // 1,280,000 float4s
#define NSMBLK ((NPIX_+255)/256)     // 79 softmax blocks
#define NTTILE ((HW_+63)/64)         // 27 transpose tiles per bn

// ---------------------------------------------------------------------------
// Kernel 1: init — grid-stride float4 zero-fill of acc (replaces the slow
// runtime fillBufferAligned: 43.5us -> ~4us) + block 0 computes the 12
// 4x4 inverses (numpy.linalg.inv f32 = OpenBLAS sgesv, VERIFIED R17).
// ---------------------------------------------------------------------------
__global__ void k_init(const float* __restrict__ l2i, float* __restrict__ minv_out,
                       float4* __restrict__ acc4) {
#pragma clang fp contract(off)
    if (blockIdx.x == 0 && threadIdx.x < B_ * N_) {
        int m = threadIdx.x;
        float a[4][4];
        for (int r = 0; r < 4; r++)
            for (int c = 0; c < 4; c++)
                a[r][c] = l2i[m * 16 + r * 4 + c];
        int ipiv[4];
        for (int j = 0; j < 4; j++) {
            int jp = j; float amax = fabsf(a[j][j]);
            for (int i = j + 1; i < 4; i++) {
                float v = fabsf(a[i][j]);
                if (v > amax) { amax = v; jp = i; }
            }
            ipiv[j] = jp;
            if (jp != j)
                for (int c = 0; c < 4; c++) { float t = a[j][c]; a[j][c] = a[jp][c]; a[jp][c] = t; }
            if (a[j][j] != 0.0f) {
                float rcp = 1.0f / a[j][j];
                for (int i = j + 1; i < 4; i++) a[i][j] = a[i][j] * rcp;
            }
            for (int k = j + 1; k < 4; k++) {
                float temp = -a[j][k];
                if (temp != 0.0f)
                    for (int i = j + 1; i < 4; i++)
                        a[i][k] = fmaf(a[i][j], temp, a[i][k]);
            }
        }
        float bmat[4][4];
        for (int r = 0; r < 4; r++)
            for (int c = 0; c < 4; c++) bmat[r][c] = (r == c) ? 1.0f : 0.0f;
        for (int j = 0; j < 4; j++) {
            int jp = ipiv[j];
            if (jp != j)
                for (int c = 0; c < 4; c++) { float t = bmat[j][c]; bmat[j][c] = bmat[jp][c]; bmat[jp][c] = t; }
        }
        for (int c = 0; c < 4; c++)
            for (int k = 0; k < 4; k++) {
                float bk = bmat[k][c];
                if (bk != 0.0f)
                    for (int i = k + 1; i < 4; i++)
                        bmat[i][c] = fmaf(-bk, a[i][k], bmat[i][c]);
            }
        float dinv[4];
        for (int k = 0; k < 4; k++) dinv[k] = 1.0f / a[k][k];
        for (int c = 0; c < 4; c++)
            for (int k = 3; k >= 0; k--) {
                float bk = bmat[k][c];
                if (bk != 0.0f) {
                    bk = bk * dinv[k];
                    bmat[k][c] = bk;
                    for (int i = 0; i < k; i++)
                        bmat[i][c] = fmaf(-bk, a[i][k], bmat[i][c]);
                }
            }
        for (int r = 0; r < 4; r++)
            for (int c = 0; c < 4; c++)
                minv_out[m * 16 + r * 4 + c] = bmat[r][c];
    }

    // grid-stride zero fill of acc
    float4 z = make_float4(0.f, 0.f, 0.f, 0.f);
    int stride = gridDim.x * blockDim.x;
    for (int i = blockIdx.x * blockDim.x + threadIdx.x; i < ACC_N4; i += stride)
        acc4[i] = z;
}

// ---------------------------------------------------------------------------
// Kernel 2: fused softmax + feats-transpose (independent outputs, one launch).
// blocks [0, NSMBLK): softmax over D per pixel -> wt (NPIX, D)
// blocks [NSMBLK, NSMBLK + 12*NTTILE): LDS-tiled transpose -> ft (BN,HW,C)
// ---------------------------------------------------------------------------
__global__ void k_prep(const float* __restrict__ depth, float* __restrict__ wt,
                       const float* __restrict__ feats, float* __restrict__ ft) {
    __shared__ float tile[64][65];
    if (blockIdx.x < NSMBLK) {
        int p = blockIdx.x * blockDim.x + threadIdx.x;
        if (p >= NPIX_) return;
        int bn = p / HW_;
        int hw = p - bn * HW_;
        const float* dptr = depth + (size_t)bn * D_ * HW_ + hw;
        float v[D_];
        float mx = -1e30f;
        #pragma unroll
        for (int d = 0; d < D_; d++) { v[d] = dptr[(size_t)d * HW_]; mx = fmaxf(mx, v[d]); }
        float s = 0.f;
        #pragma unroll
        for (int d = 0; d < D_; d++) { v[d] = expf(v[d] - mx); s += v[d]; }
        float is = 1.f / s;
        float* o = wt + (size_t)p * D_;
        #pragma unroll
        for (int d = 0; d < D_; d++) o[d] = v[d] * is;
    } else {
        int bid = blockIdx.x - NSMBLK;
        int bn = bid / NTTILE;
        int p0 = (bid % NTTILE) * 64;
        int tx = threadIdx.x & 63;
        int ty = threadIdx.x >> 6;  // 0..3
        const float* src = feats + (size_t)bn * C_ * HW_;
        #pragma unroll
        for (int k = 0; k < 16; k++) {
            int c = ty * 16 + k;
            int p = p0 + tx;
            if (p < HW_) tile[c][tx] = src[(size_t)c * HW_ + p];
        }
        __syncthreads();
        float* dst = ft + (size_t)bn * HW_ * C_;
        #pragma unroll
        for (int k = 0; k < 16; k++) {
            int pl = ty * 16 + k;
            int p = p0 + pl;
            if (p < HW_) dst[(size_t)p * C_ + tx] = tile[tx][pl];
        }
    }
}

// ---------------------------------------------------------------------------
// Kernel 3: scatter4 — one wave per (bn, w, d-chunk of 4).  [VERIFIED R20]
// ---------------------------------------------------------------------------
__global__ void k_scatter4(const float* __restrict__ frustum,
                           const float* __restrict__ minv,
                           const float* __restrict__ wt,
                           const float* __restrict__ ft,
                           const float* __restrict__ dxp,
                           const float* __restrict__ bxp,
                           float* __restrict__ acc) {
#pragma clang fp contract(off)
    int gtid = blockIdx.x * blockDim.x + threadIdx.x;
    int wvid = gtid >> 6;
    int lane = threadIdx.x & 63;
    if (wvid >= B_ * N_ * FW_ * DSPLIT) return;
    int dq = wvid % DSPLIT;
    int w  = (wvid / DSPLIT) % FW_;
    int bn = wvid / (DSPLIT * FW_);
    int b  = bn / N_;
    int bnbase = bn * HW_;
    int d0 = dq * DCHUNK;

    float ftreg[FH_];
    #pragma unroll
    for (int h = 0; h < FH_; h++)
        ftreg[h] = ft[(size_t)(bnbase + h * FW_ + w) * C_ + lane];

    float u = frustum[w * 3 + 0];
    float v = 0.f;
    float4 w4 = make_float4(0.f, 0.f, 0.f, 0.f);
    if (lane < FH_) {
        v = frustum[((size_t)lane * FW_ + w) * 3 + 1];
        int pix = bnbase + lane * FW_ + w;
        w4 = *reinterpret_cast<const float4*>(&wt[(size_t)pix * D_ + d0]);
    }
    const float* M = minv + (size_t)bn * 16;
    float M0 = M[0], M1 = M[1], M2 = M[2],  M3 = M[3];
    float M4 = M[4], M5 = M[5], M6 = M[6],  M7 = M[7];
    float M8 = M[8], M9 = M[9], M10 = M[10], M11 = M[11];
    float dx0 = dxp[0], dx1 = dxp[1], dx2 = dxp[2];
    float lb0 = bxp[0] - dx0 * 0.5f;
    float lb1 = bxp[1] - dx1 * 0.5f;
    float lb2 = bxp[2] - dx2 * 0.5f;

    #pragma unroll
    for (int k = 0; k < DCHUNK; k++) {
        int d = d0 + k;
        float mywt = (k == 0) ? w4.x : (k == 1) ? w4.y : (k == 2) ? w4.z : w4.w;
        int myenc = -1;
        if (lane < FH_) {
            float dd = (float)(d + 1);
            float dm = fmaxf(dd, 1e-5f);
            float p0 = u * dm;
            float p1 = v * dm;
            float p2 = dd;
            float x0 = M0 * p0, x1 = M1 * p1, x2 = M2 * p2, x3 = M3 * 1.0f;
            float gx = (x0 + x1) + (x2 + x3);
            float y0 = M4 * p0, y1 = M5 * p1, y2 = M6 * p2, y3 = M7 * 1.0f;
            float gy = (y0 + y1) + (y2 + y3);
            float z0 = M8 * p0, z1 = M9 * p1, z2 = M10 * p2, z3 = M11 * 1.0f;
            float gz = (z0 + z1) + (z2 + z3);
            float qx = (gx - lb0) / dx0;
            float qy = (gy - lb1) / dx1;
            float qz = (gz - lb2) / dx2;
            int ix = (int)qx;
            int iy = (int)qy;
            int iz = (int)qz;
            if (ix >= 0 && ix < NX_ && iy >= 0 && iy < NY_ && iz == 0)
                myenc = (((b * NX_) + ix) * NY_ + iy) * C_;
        }

        unsigned long long processed = 0;
        for (int j = 0; j < FH_; ++j) {
            if (processed & (1ull << j)) continue;
            int e = __shfl(myenc, j, 64);
            unsigned long long mm = __ballot(lane < FH_ && myenc == e);
            processed |= mm;
            if (e < 0) continue;
            float s = 0.f;
            #pragma unroll
            for (int h = 0; h < FH_; h++) {
                float wh = __shfl(mywt, h, 64);
                s = fmaf(((mm >> h) & 1ull) ? wh : 0.0f, ftreg[h], s);
            }
            atomicAdd(&acc[(size_t)e + lane], s);
        }
    }
}

// ---------------------------------------------------------------------------
// Kernel 4: transpose acc (B, NX*NY, C) -> out (B, C, NX*NY).
// ---------------------------------------------------------------------------
__global__ void k_out(const float* __restrict__ acc, float* __restrict__ out) {
    __shared__ float tile[64][65];
    int b = blockIdx.y;
    int p0 = blockIdx.x * 64;
    int tx = threadIdx.x & 63;
    int ty = threadIdx.x >> 6;
    const float* src = acc + (size_t)b * (NX_ * NY_) * C_;
    #pragma unroll
    for (int k = 0; k < 16; k++) {
        int pl = ty * 16 + k;
        tile[pl][tx] = src[(size_t)(p0 + pl) * C_ + tx];
    }
    __syncthreads();
    float* dst = out + (size_t)b * C_ * (NX_ * NY_);
    #pragma unroll
    for (int k = 0; k < 16; k++) {
        int c = ty * 16 + k;
        dst[(size_t)c * (NX_ * NY_) + p0 + tx] = tile[tx][c];
    }
}

// ---------------------------------------------------------------------------
extern "C" void kernel_launch(void* const* d_in, const int* in_sizes, int n_in,
                              void* d_out, int out_size, void* d_ws, size_t ws_size,
                              hipStream_t stream) {
    const float* feats = (const float*)d_in[0];
    const float* depth = (const float*)d_in[1];
    const float* l2i   = (const float*)d_in[2];
    const float* frust = (const float*)d_in[3];
    const float* dx    = (const float*)d_in[4];
    const float* bx    = (const float*)d_in[5];
    float* out = (float*)d_out;

    char* ws = (char*)d_ws;
    float* minv = (float*)ws;                                     // 12*16*4 = 768 B (pad 2048)
    float* wt  = (float*)(ws + 2048);                             // 20160*60*4 = 4,838,400
    float* ft  = (float*)(ws + 2048 + 4838400);                   // 20160*64*4 = 5,160,960
    float* acc = (float*)(ws + 2048 + 4838400 + 5160960);         // 2*200*200*64*4 = 20,480,000

    k_init<<<2048, 256, 0, stream>>>(l2i, minv, (float4*)acc);
    k_prep<<<NSMBLK + N_ * B_ * NTTILE, 256, 0, stream>>>(depth, wt, feats, ft);
    int nwaves = B_ * N_ * FW_ * DSPLIT;                          // 10800
    k_scatter4<<<(nwaves * 64 + 255) / 256, 256, 0, stream>>>(frust, minv, wt, ft, dx, bx, acc);
    k_out<<<dim3((NX_ * NY_) / 64, B_), 256, 0, stream>>>(acc, out);
}

// Round 22
// 56.289 us; speedup vs baseline: 4.6890x; 1.1008x over previous
//
#include <hip/hip_runtime.h>
#include <math.h>

// Static problem dims
#define B_   2
#define N_   6
#define D_   60
#define FH_  28
#define FW_  60
#define C_   64
#define NX_  200
#define NY_  200
#define HW_  (FH_*FW_)       // 1680
#define NPIX_ (B_*N_*HW_)    // 20160
#define DSPLIT 15
#define DCHUNK (D_/DSPLIT)   // 4
#define ACC_N4 ((B_*NX_*NY_*C_)/4)   // 1,280,000 float4s
#define NFILLB 1024                  // fill blocks
#define NSMBLK ((NPIX_+255)/256)     // 79 softmax blocks
#define NTTILE ((HW_+63)/64)         // 27 transpose tiles per bn

// ---------------------------------------------------------------------------
// Kernel 1: k_pre — fused, block-range dispatched:
//   [0, NFILLB):    grid-stride float4 zero-fill of acc; block 0 lanes 0..11
//                   also run the 12 4x4 inverses (OpenBLAS sgesv, VERIFIED R17)
//   [NFILLB, +79):  softmax over D per pixel -> wt (NPIX, D)
//   [+79, +324):    LDS-tiled feats transpose -> ft (BN, HW, C)
// All three are independent; fusing removes two launch gaps and overlaps the
// write-only fill with the read/VALU softmax across CUs.
// ---------------------------------------------------------------------------
__global__ void k_pre(const float* __restrict__ l2i, float* __restrict__ minv_out,
                      float4* __restrict__ acc4,
                      const float* __restrict__ depth, float* __restrict__ wt,
                      const float* __restrict__ feats, float* __restrict__ ft) {
#pragma clang fp contract(off)
    __shared__ float tile[64][65];
    if (blockIdx.x < NFILLB) {
        if (blockIdx.x == 0 && threadIdx.x < B_ * N_) {
            int m = threadIdx.x;
            float a[4][4];
            for (int r = 0; r < 4; r++)
                for (int c = 0; c < 4; c++)
                    a[r][c] = l2i[m * 16 + r * 4 + c];
            int ipiv[4];
            for (int j = 0; j < 4; j++) {
                int jp = j; float amax = fabsf(a[j][j]);
                for (int i = j + 1; i < 4; i++) {
                    float v = fabsf(a[i][j]);
                    if (v > amax) { amax = v; jp = i; }
                }
                ipiv[j] = jp;
                if (jp != j)
                    for (int c = 0; c < 4; c++) { float t = a[j][c]; a[j][c] = a[jp][c]; a[jp][c] = t; }
                if (a[j][j] != 0.0f) {
                    float rcp = 1.0f / a[j][j];
                    for (int i = j + 1; i < 4; i++) a[i][j] = a[i][j] * rcp;
                }
                for (int k = j + 1; k < 4; k++) {
                    float temp = -a[j][k];
                    if (temp != 0.0f)
                        for (int i = j + 1; i < 4; i++)
                            a[i][k] = fmaf(a[i][j], temp, a[i][k]);
                }
            }
            float bmat[4][4];
            for (int r = 0; r < 4; r++)
                for (int c = 0; c < 4; c++) bmat[r][c] = (r == c) ? 1.0f : 0.0f;
            for (int j = 0; j < 4; j++) {
                int jp = ipiv[j];
                if (jp != j)
                    for (int c = 0; c < 4; c++) { float t = bmat[j][c]; bmat[j][c] = bmat[jp][c]; bmat[jp][c] = t; }
            }
            for (int c = 0; c < 4; c++)
                for (int k = 0; k < 4; k++) {
                    float bk = bmat[k][c];
                    if (bk != 0.0f)
                        for (int i = k + 1; i < 4; i++)
                            bmat[i][c] = fmaf(-bk, a[i][k], bmat[i][c]);
                }
            float dinv[4];
            for (int k = 0; k < 4; k++) dinv[k] = 1.0f / a[k][k];
            for (int c = 0; c < 4; c++)
                for (int k = 3; k >= 0; k--) {
                    float bk = bmat[k][c];
                    if (bk != 0.0f) {
                        bk = bk * dinv[k];
                        bmat[k][c] = bk;
                        for (int i = 0; i < k; i++)
                            bmat[i][c] = fmaf(-bk, a[i][k], bmat[i][c]);
                    }
                }
            for (int r = 0; r < 4; r++)
                for (int c = 0; c < 4; c++)
                    minv_out[m * 16 + r * 4 + c] = bmat[r][c];
        }
        // grid-stride zero fill of acc over the fill-block range
        float4 z = make_float4(0.f, 0.f, 0.f, 0.f);
        int stride = NFILLB * blockDim.x;
        for (int i = blockIdx.x * blockDim.x + threadIdx.x; i < ACC_N4; i += stride)
            acc4[i] = z;
    } else if (blockIdx.x < NFILLB + NSMBLK) {
        int p = (blockIdx.x - NFILLB) * blockDim.x + threadIdx.x;
        if (p >= NPIX_) return;
        int bn = p / HW_;
        int hw = p - bn * HW_;
        const float* dptr = depth + (size_t)bn * D_ * HW_ + hw;
        float v[D_];
        float mx = -1e30f;
        #pragma unroll
        for (int d = 0; d < D_; d++) { v[d] = dptr[(size_t)d * HW_]; mx = fmaxf(mx, v[d]); }
        float s = 0.f;
        #pragma unroll
        for (int d = 0; d < D_; d++) { v[d] = expf(v[d] - mx); s += v[d]; }
        float is = 1.f / s;
        float* o = wt + (size_t)p * D_;
        #pragma unroll
        for (int d = 0; d < D_; d++) o[d] = v[d] * is;
    } else {
        int bid = blockIdx.x - NFILLB - NSMBLK;
        int bn = bid / NTTILE;
        int p0 = (bid % NTTILE) * 64;
        int tx = threadIdx.x & 63;
        int ty = threadIdx.x >> 6;  // 0..3
        const float* src = feats + (size_t)bn * C_ * HW_;
        #pragma unroll
        for (int k = 0; k < 16; k++) {
            int c = ty * 16 + k;
            int p = p0 + tx;
            if (p < HW_) tile[c][tx] = src[(size_t)c * HW_ + p];
        }
        __syncthreads();
        float* dst = ft + (size_t)bn * HW_ * C_;
        #pragma unroll
        for (int k = 0; k < 16; k++) {
            int pl = ty * 16 + k;
            int p = p0 + pl;
            if (p < HW_) dst[(size_t)p * C_ + tx] = tile[tx][pl];
        }
    }
}

// ---------------------------------------------------------------------------
// Kernel 2: scatter4 — one wave per (bn, w, d-chunk of 4).  [VERIFIED R20]
// ---------------------------------------------------------------------------
__global__ void k_scatter4(const float* __restrict__ frustum,
                           const float* __restrict__ minv,
                           const float* __restrict__ wt,
                           const float* __restrict__ ft,
                           const float* __restrict__ dxp,
                           const float* __restrict__ bxp,
                           float* __restrict__ acc) {
#pragma clang fp contract(off)
    int gtid = blockIdx.x * blockDim.x + threadIdx.x;
    int wvid = gtid >> 6;
    int lane = threadIdx.x & 63;
    if (wvid >= B_ * N_ * FW_ * DSPLIT) return;
    int dq = wvid % DSPLIT;
    int w  = (wvid / DSPLIT) % FW_;
    int bn = wvid / (DSPLIT * FW_);
    int b  = bn / N_;
    int bnbase = bn * HW_;
    int d0 = dq * DCHUNK;

    float ftreg[FH_];
    #pragma unroll
    for (int h = 0; h < FH_; h++)
        ftreg[h] = ft[(size_t)(bnbase + h * FW_ + w) * C_ + lane];

    float u = frustum[w * 3 + 0];
    float v = 0.f;
    float4 w4 = make_float4(0.f, 0.f, 0.f, 0.f);
    if (lane < FH_) {
        v = frustum[((size_t)lane * FW_ + w) * 3 + 1];
        int pix = bnbase + lane * FW_ + w;
        w4 = *reinterpret_cast<const float4*>(&wt[(size_t)pix * D_ + d0]);
    }
    const float* M = minv + (size_t)bn * 16;
    float M0 = M[0], M1 = M[1], M2 = M[2],  M3 = M[3];
    float M4 = M[4], M5 = M[5], M6 = M[6],  M7 = M[7];
    float M8 = M[8], M9 = M[9], M10 = M[10], M11 = M[11];
    float dx0 = dxp[0], dx1 = dxp[1], dx2 = dxp[2];
    float lb0 = bxp[0] - dx0 * 0.5f;
    float lb1 = bxp[1] - dx1 * 0.5f;
    float lb2 = bxp[2] - dx2 * 0.5f;

    #pragma unroll
    for (int k = 0; k < DCHUNK; k++) {
        int d = d0 + k;
        float mywt = (k == 0) ? w4.x : (k == 1) ? w4.y : (k == 2) ? w4.z : w4.w;
        int myenc = -1;
        if (lane < FH_) {
            float dd = (float)(d + 1);
            float dm = fmaxf(dd, 1e-5f);
            float p0 = u * dm;
            float p1 = v * dm;
            float p2 = dd;
            float x0 = M0 * p0, x1 = M1 * p1, x2 = M2 * p2, x3 = M3 * 1.0f;
            float gx = (x0 + x1) + (x2 + x3);
            float y0 = M4 * p0, y1 = M5 * p1, y2 = M6 * p2, y3 = M7 * 1.0f;
            float gy = (y0 + y1) + (y2 + y3);
            float z0 = M8 * p0, z1 = M9 * p1, z2 = M10 * p2, z3 = M11 * 1.0f;
            float gz = (z0 + z1) + (z2 + z3);
            float qx = (gx - lb0) / dx0;
            float qy = (gy - lb1) / dx1;
            float qz = (gz - lb2) / dx2;
            int ix = (int)qx;
            int iy = (int)qy;
            int iz = (int)qz;
            if (ix >= 0 && ix < NX_ && iy >= 0 && iy < NY_ && iz == 0)
                myenc = (((b * NX_) + ix) * NY_ + iy) * C_;
        }

        unsigned long long processed = 0;
        for (int j = 0; j < FH_; ++j) {
            if (processed & (1ull << j)) continue;
            int e = __shfl(myenc, j, 64);
            unsigned long long mm = __ballot(lane < FH_ && myenc == e);
            processed |= mm;
            if (e < 0) continue;
            float s = 0.f;
            #pragma unroll
            for (int h = 0; h < FH_; h++) {
                float wh = __shfl(mywt, h, 64);
                s = fmaf(((mm >> h) & 1ull) ? wh : 0.0f, ftreg[h], s);
            }
            atomicAdd(&acc[(size_t)e + lane], s);
        }
    }
}

// ---------------------------------------------------------------------------
// Kernel 3: transpose acc (B, NX*NY, C) -> out (B, C, NX*NY).
// ---------------------------------------------------------------------------
__global__ void k_out(const float* __restrict__ acc, float* __restrict__ out) {
    __shared__ float tile[64][65];
    int b = blockIdx.y;
    int p0 = blockIdx.x * 64;
    int tx = threadIdx.x & 63;
    int ty = threadIdx.x >> 6;
    const float* src = acc + (size_t)b * (NX_ * NY_) * C_;
    #pragma unroll
    for (int k = 0; k < 16; k++) {
        int pl = ty * 16 + k;
        tile[pl][tx] = src[(size_t)(p0 + pl) * C_ + tx];
    }
    __syncthreads();
    float* dst = out + (size_t)b * C_ * (NX_ * NY_);
    #pragma unroll
    for (int k = 0; k < 16; k++) {
        int c = ty * 16 + k;
        dst[(size_t)c * (NX_ * NY_) + p0 + tx] = tile[tx][c];
    }
}

// ---------------------------------------------------------------------------
extern "C" void kernel_launch(void* const* d_in, const int* in_sizes, int n_in,
                              void* d_out, int out_size, void* d_ws, size_t ws_size,
                              hipStream_t stream) {
    const float* feats = (const float*)d_in[0];
    const float* depth = (const float*)d_in[1];
    const float* l2i   = (const float*)d_in[2];
    const float* frust = (const float*)d_in[3];
    const float* dx    = (const float*)d_in[4];
    const float* bx    = (const float*)d_in[5];
    float* out = (float*)d_out;

    char* ws = (char*)d_ws;
    float* minv = (float*)ws;                                     // 12*16*4 = 768 B (pad 2048)
    float* wt  = (float*)(ws + 2048);                             // 20160*60*4 = 4,838,400
    float* ft  = (float*)(ws + 2048 + 4838400);                   // 20160*64*4 = 5,160,960
    float* acc = (float*)(ws + 2048 + 4838400 + 5160960);         // 2*200*200*64*4 = 20,480,000

    k_pre<<<NFILLB + NSMBLK + B_ * N_ * NTTILE, 256, 0, stream>>>(
        l2i, minv, (float4*)acc, depth, wt, feats, ft);
    int nwaves = B_ * N_ * FW_ * DSPLIT;                          // 10800
    k_scatter4<<<(nwaves * 64 + 255) / 256, 256, 0, stream>>>(frust, minv, wt, ft, dx, bx, acc);
    k_out<<<dim3((NX_ * NY_) / 64, B_), 256, 0, stream>>>(acc, out);
}